// Round 3
// baseline (143.971 us; speedup 1.0000x reference)
//
#include <hip/hip_runtime.h>
#include <math.h>

#define B_    32
#define NV    32768
#define LA    64
#define DIM   128
#define OUTD  7
#define TOPK  10
#define CHUNK 2048
#define NCH   (NV / CHUNK)   // 16
#define NMW   (NV / 32)      // 1024 mask words per batch

// ---------------- K1: per-(b,l) sample threshold (upper bound on 10th-NN d2) ----
// grid (LA, B_), block 64 (one wave). Contiguous sample block (coalesced).
// Also zeroes the candidate counters and the per-batch dedup bitmask.
__global__ void k1_threshold(const float* __restrict__ pos,
                             const float* __restrict__ lig,
                             float* __restrict__ T, unsigned int* __restrict__ cnt,
                             unsigned int* __restrict__ maskG) {
  const int l = blockIdx.x, b = blockIdx.y;
  const int lane = threadIdx.x;
  const int bl = b * LA + l;
  if (lane == 0) cnt[bl] = 0u;
  if (lane < 16) maskG[b * NMW + l * 16 + lane] = 0u;  // 64 blocks x 16 = 1024 words
  const float lx = lig[bl * 3 + 0];
  const float ly = lig[bl * 3 + 1];
  const float lz = lig[bl * 3 + 2];
  float s[TOPK];
#pragma unroll
  for (int i = 0; i < TOPK; ++i) s[i] = INFINITY;
  const float* pb = pos + (size_t)b * NV * 3;
  // sample: first 2048 vertices (any subset gives a valid upper bound)
  for (int k = 0; k < 32; ++k) {
    int v = lane + 64 * k;
    float dx = pb[v * 3 + 0] - lx;
    float dy = pb[v * 3 + 1] - ly;
    float dz = pb[v * 3 + 2] - lz;
    float d2 = fmaf(dx, dx, fmaf(dy, dy, dz * dz));
    if (d2 < s[TOPK - 1]) {
      s[TOPK - 1] = d2;
#pragma unroll
      for (int i = TOPK - 1; i >= 1; --i)
        if (s[i] < s[i - 1]) { float t = s[i]; s[i] = s[i - 1]; s[i - 1] = t; }
    }
  }
  // 10 rounds of wave-min with consume: T = 10th smallest sample d2
  float T10 = 0.f;
  for (int r = 0; r < TOPK; ++r) {
    float v = s[0];
#pragma unroll
    for (int o = 1; o < 64; o <<= 1) v = fminf(v, __shfl_xor(v, o, 64));
    T10 = v;
    if (s[0] == v) {  // consume (duplicate-consume only enlarges T: safe)
#pragma unroll
      for (int i = 0; i < TOPK - 1; ++i) s[i] = s[i + 1];
      s[TOPK - 1] = INFINITY;
    }
  }
  if (lane == 0) T[bl] = T10;
}

// ---------------- K2: filter pass -- append candidates with d2 <= T + slack ----
// grid (NCH, B_), block 256. Thread = (lg = tid>>4 in 0..15, vl = tid&15).
__global__ void k2_filter(const float* __restrict__ pos,
                          const float* __restrict__ lig,
                          const float* __restrict__ T,
                          unsigned int* __restrict__ cnt,
                          int* __restrict__ cand, int cap) {
  __shared__ float4 vp[CHUNK];  // x,y,z,pp  (32 KB)
  const int c = blockIdx.x, b = blockIdx.y;
  const int tid = threadIdx.x;
  const int base = c * CHUNK;
  const float* pb = pos + ((size_t)b * NV + base) * 3;
  for (int j = tid; j < CHUNK * 3; j += 256) {
    int v = j / 3, comp = j - 3 * v;
    float val = pb[j];
    if (comp == 0) vp[v].x = val;
    else if (comp == 1) vp[v].y = val;
    else vp[v].z = val;
  }
  __syncthreads();
  for (int v = tid; v < CHUNK; v += 256) {
    float px = vp[v].x, py = vp[v].y, pz = vp[v].z;
    vp[v].w = fmaf(px, px, fmaf(py, py, pz * pz));
  }
  __syncthreads();
  const int lg = tid >> 4, vl = tid & 15;
  float Ax[4], Ay[4], Az[4], TH[4];
#pragma unroll
  for (int j = 0; j < 4; ++j) {
    int l = lg + 16 * j;
    float lx = lig[(b * LA + l) * 3 + 0];
    float ly = lig[(b * LA + l) * 3 + 1];
    float lz = lig[(b * LA + l) * 3 + 2];
    Ax[j] = -2.f * lx; Ay[j] = -2.f * ly; Az[j] = -2.f * lz;
    TH[j] = T[b * LA + l] + 0.01f - (lx * lx + ly * ly + lz * lz);
  }
  for (int k = 0; k < CHUNK / 16; ++k) {
    int v = vl + 16 * k;
    float4 p = vp[v];
#pragma unroll
    for (int j = 0; j < 4; ++j) {
      float t = fmaf(p.x, Ax[j], fmaf(p.y, Ay[j], fmaf(p.z, Az[j], p.w)));
      if (t <= TH[j]) {
        int l = lg + 16 * j;
        unsigned pidx = atomicAdd(&cnt[b * LA + l], 1u);
        if (pidx < (unsigned)cap) cand[(size_t)(b * LA + l) * cap + pidx] = base + v;
      }
    }
  }
}

// ---------------- K3: exact top-10 over candidates + set dedup bits -------------
// grid 2048 (=B_*LA), block 64 (one wave).
__global__ void k3_select(const float* __restrict__ pos,
                          const float* __restrict__ lig,
                          const unsigned int* __restrict__ cnt,
                          const int* __restrict__ cand, int cap,
                          unsigned int* __restrict__ maskG) {
  const int bl = blockIdx.x;
  const int b = bl / LA;
  const int lane = threadIdx.x;
  const float lx = lig[bl * 3 + 0], ly = lig[bl * 3 + 1], lz = lig[bl * 3 + 2];
  int n = (int)min(cnt[bl], (unsigned)cap);
  unsigned long long s[TOPK];
#pragma unroll
  for (int i = 0; i < TOPK; ++i) s[i] = 0xFFFFFFFFFFFFFFFFull;
  const float* pb = pos + (size_t)b * NV * 3;
  for (int i = lane; i < n; i += 64) {
    int v = cand[(size_t)bl * cap + i];
    float dx = pb[v * 3 + 0] - lx;
    float dy = pb[v * 3 + 1] - ly;
    float dz = pb[v * 3 + 2] - lz;
    float d2 = fmaf(dx, dx, fmaf(dy, dy, dz * dz));
    unsigned long long key =
        ((unsigned long long)__float_as_uint(d2) << 32) | (unsigned int)v;
    if (key < s[TOPK - 1]) {
      s[TOPK - 1] = key;
#pragma unroll
      for (int i2 = TOPK - 1; i2 >= 1; --i2)
        if (s[i2] < s[i2 - 1]) {
          unsigned long long t = s[i2]; s[i2] = s[i2 - 1]; s[i2 - 1] = t;
        }
    }
  }
  int prev = 0, myidx = 0;
  for (int r = 0; r < TOPK; ++r) {
    unsigned long long v = s[0];
#pragma unroll
    for (int o = 1; o < 64; o <<= 1) {
      unsigned long long other = __shfl_xor(v, o, 64);
      v = (other < v) ? other : v;
    }
    if (s[0] == v) {
#pragma unroll
      for (int i = 0; i < TOPK - 1; ++i) s[i] = s[i + 1];
      s[TOPK - 1] = 0xFFFFFFFFFFFFFFFFull;
    }
    int idx = (int)(unsigned int)(v & 0xFFFFFFFFu);
    if ((v >> 32) == 0xFFFFFFFFull) idx = prev;  // pad guard (n<10 impossible)
    prev = idx;
    if (lane == r) myidx = idx;
  }
  if (lane < TOPK)
    atomicOr(&maskG[b * NMW + (myidx >> 5)], 1u << (myidx & 31));
}

// ---------------- K4: mask-scan compaction + gather mean + top_net MLP ----------
// grid B_, block 1024 (16 waves).
__global__ void k4_gather_mlp(const float* __restrict__ x,
                              const unsigned int* __restrict__ maskG,
                              const float* __restrict__ W1, const float* __restrict__ b1,
                              const float* __restrict__ gamma, const float* __restrict__ beta,
                              const float* __restrict__ rm, const float* __restrict__ rv,
                              const float* __restrict__ W2, const float* __restrict__ b2,
                              float* __restrict__ out) {
  __shared__ int list[NMW];          // 4 KB (max 640 used)
  __shared__ int wtot[16], wbase[16];
  __shared__ int cntS;
  __shared__ double red[8][DIM];     // 8 KB
  __shared__ float embS[DIM];
  __shared__ float hS[DIM];
  const int b = blockIdx.x, tid = threadIdx.x;
  const int w = tid >> 6, lane = tid & 63;
  // --- block-wide exclusive-scan compaction of the bitmask (deterministic) ---
  unsigned int bits = maskG[b * NMW + tid];
  int c = __popc(bits);
  int incl = c;
#pragma unroll
  for (int o = 1; o < 64; o <<= 1) {
    int up = __shfl_up(incl, o, 64);
    if (lane >= o) incl += up;
  }
  if (lane == 63) wtot[w] = incl;
  __syncthreads();
  if (tid == 0) {
    int s = 0;
    for (int i = 0; i < 16; ++i) { wbase[i] = s; s += wtot[i]; }
    cntS = s;
  }
  __syncthreads();
  int p = wbase[w] + incl - c;
  while (bits) {
    int bit = __ffs(bits) - 1;
    list[p++] = tid * 32 + bit;
    bits &= bits - 1;
  }
  __syncthreads();
  const int n = cntS;
  // --- gather-sum: slot = tid>>7 (8 row slots), col = tid&127 ---
  const int slot = tid >> 7, col = tid & 127;
  const float* xb = x + (size_t)b * NV * DIM;
  double a0 = 0, a1 = 0, a2 = 0, a3 = 0;
  int i = slot;
  for (; i + 24 < n; i += 32) {
    float v0 = xb[(size_t)list[i +  0] * DIM + col];
    float v1 = xb[(size_t)list[i +  8] * DIM + col];
    float v2 = xb[(size_t)list[i + 16] * DIM + col];
    float v3 = xb[(size_t)list[i + 24] * DIM + col];
    a0 += (double)v0; a1 += (double)v1; a2 += (double)v2; a3 += (double)v3;
  }
  for (; i < n; i += 8) a0 += (double)xb[(size_t)list[i] * DIM + col];
  red[slot][col] = ((a0 + a1) + (a2 + a3));
  __syncthreads();
  if (tid < DIM) {
    double s = 0;
#pragma unroll
    for (int r = 0; r < 8; ++r) s += red[r][tid];
    embS[tid] = (float)(s / (double)n);
  }
  __syncthreads();
  // --- Linear1 + BatchNorm(eval) + SiLU + Linear2 ---
  if (tid < DIM) {
    const int d = tid;
    float h = b1[d];
    for (int dd = 0; dd < DIM; ++dd) h = fmaf(embS[dd], W1[dd * DIM + d], h);
    h = (h - rm[d]) / sqrtf(rv[d] + 1e-5f) * gamma[d] + beta[d];
    h = h / (1.f + expf(-h));
    hS[d] = h;
  }
  __syncthreads();
  if (tid < OUTD) {
    float o = b2[tid];
    for (int dd = 0; dd < DIM; ++dd) o = fmaf(hS[dd], W2[dd * OUTD + tid], o);
    out[b * OUTD + tid] = o;
  }
}

extern "C" void kernel_launch(void* const* d_in, const int* in_sizes, int n_in,
                              void* d_out, int out_size, void* d_ws, size_t ws_size,
                              hipStream_t stream) {
  const float* pos  = (const float*)d_in[0];
  const float* x    = (const float*)d_in[1];
  const float* lig  = (const float*)d_in[2];
  const float* W1   = (const float*)d_in[3];
  const float* b1   = (const float*)d_in[4];
  const float* gam  = (const float*)d_in[5];
  const float* bet  = (const float*)d_in[6];
  const float* rm   = (const float*)d_in[7];
  const float* rv   = (const float*)d_in[8];
  const float* W2   = (const float*)d_in[9];
  const float* b2   = (const float*)d_in[10];
  float* out = (float*)d_out;

  // workspace carve-up
  char* ws = (char*)d_ws;
  const int NBL = B_ * LA;  // 2048
  float* T           = (float*)(ws);                    // 8 KB
  unsigned int* cnt  = (unsigned int*)(ws + 8192);      // 8 KB
  unsigned int* maskG= (unsigned int*)(ws + 16384);     // 128 KB
  int* cand          = (int*)(ws + 16384 + 131072);
  size_t fixed = 16384 + 131072;
  size_t avail = ws_size > fixed ? ws_size - fixed : 0;
  int cap = (int)(avail / ((size_t)NBL * 4));
  if (cap > 1024) cap = 1024;
  if (cap < 16) cap = 16;

  k1_threshold<<<dim3(LA, B_), 64, 0, stream>>>(pos, lig, T, cnt, maskG);
  k2_filter<<<dim3(NCH, B_), 256, 0, stream>>>(pos, lig, T, cnt, cand, cap);
  k3_select<<<NBL, 64, 0, stream>>>(pos, lig, cnt, cand, cap, maskG);
  k4_gather_mlp<<<B_, 1024, 0, stream>>>(x, maskG, W1, b1, gam, bet, rm, rv, W2, b2, out);
}

// Round 4
// 140.894 us; speedup vs baseline: 1.0218x; 1.0218x over previous
//
#include <hip/hip_runtime.h>
#include <math.h>

#define B_    32
#define NV    32768
#define LA    64
#define DIM   128
#define OUTD  7
#define TOPK  10
#define CHUNK 2048
#define NCH   (NV / CHUNK)   // 16
#define NMW   (NV / 32)      // 1024 mask words per batch
#define MAXU  (LA * TOPK)    // 640
#define NSEG  8              // gather segments per batch

// ---------------- K1: per-(b,l) sample threshold (upper bound on 10th-NN d2) ----
// grid (LA, B_), block 64 (one wave). Contiguous sample block (coalesced).
// Also zeroes the candidate counters and the per-batch dedup bitmask.
__global__ void k1_threshold(const float* __restrict__ pos,
                             const float* __restrict__ lig,
                             float* __restrict__ T, unsigned int* __restrict__ cnt,
                             unsigned int* __restrict__ maskG) {
  const int l = blockIdx.x, b = blockIdx.y;
  const int lane = threadIdx.x;
  const int bl = b * LA + l;
  if (lane == 0) cnt[bl] = 0u;
  if (lane < 16) maskG[b * NMW + l * 16 + lane] = 0u;  // 64 blocks x 16 = 1024 words
  const float lx = lig[bl * 3 + 0];
  const float ly = lig[bl * 3 + 1];
  const float lz = lig[bl * 3 + 2];
  float s[TOPK];
#pragma unroll
  for (int i = 0; i < TOPK; ++i) s[i] = INFINITY;
  const float* pb = pos + (size_t)b * NV * 3;
  for (int k = 0; k < 32; ++k) {
    int v = lane + 64 * k;
    float dx = pb[v * 3 + 0] - lx;
    float dy = pb[v * 3 + 1] - ly;
    float dz = pb[v * 3 + 2] - lz;
    float d2 = fmaf(dx, dx, fmaf(dy, dy, dz * dz));
    if (d2 < s[TOPK - 1]) {
      s[TOPK - 1] = d2;
#pragma unroll
      for (int i = TOPK - 1; i >= 1; --i)
        if (s[i] < s[i - 1]) { float t = s[i]; s[i] = s[i - 1]; s[i - 1] = t; }
    }
  }
  float T10 = 0.f;
  for (int r = 0; r < TOPK; ++r) {
    float v = s[0];
#pragma unroll
    for (int o = 1; o < 64; o <<= 1) v = fminf(v, __shfl_xor(v, o, 64));
    T10 = v;
    if (s[0] == v) {
#pragma unroll
      for (int i = 0; i < TOPK - 1; ++i) s[i] = s[i + 1];
      s[TOPK - 1] = INFINITY;
    }
  }
  if (lane == 0) T[bl] = T10;
}

// ---------------- K2: filter pass -- append candidates with d2 <= T + slack ----
// grid (NCH, B_), block 256.
__global__ void k2_filter(const float* __restrict__ pos,
                          const float* __restrict__ lig,
                          const float* __restrict__ T,
                          unsigned int* __restrict__ cnt,
                          int* __restrict__ cand, int cap) {
  __shared__ float4 vp[CHUNK];  // 32 KB
  const int c = blockIdx.x, b = blockIdx.y;
  const int tid = threadIdx.x;
  const int base = c * CHUNK;
  const float* pb = pos + ((size_t)b * NV + base) * 3;
  for (int j = tid; j < CHUNK * 3; j += 256) {
    int v = j / 3, comp = j - 3 * v;
    float val = pb[j];
    if (comp == 0) vp[v].x = val;
    else if (comp == 1) vp[v].y = val;
    else vp[v].z = val;
  }
  __syncthreads();
  for (int v = tid; v < CHUNK; v += 256) {
    float px = vp[v].x, py = vp[v].y, pz = vp[v].z;
    vp[v].w = fmaf(px, px, fmaf(py, py, pz * pz));
  }
  __syncthreads();
  const int lg = tid >> 4, vl = tid & 15;
  float Ax[4], Ay[4], Az[4], TH[4];
#pragma unroll
  for (int j = 0; j < 4; ++j) {
    int l = lg + 16 * j;
    float lx = lig[(b * LA + l) * 3 + 0];
    float ly = lig[(b * LA + l) * 3 + 1];
    float lz = lig[(b * LA + l) * 3 + 2];
    Ax[j] = -2.f * lx; Ay[j] = -2.f * ly; Az[j] = -2.f * lz;
    TH[j] = T[b * LA + l] + 0.01f - (lx * lx + ly * ly + lz * lz);
  }
  for (int k = 0; k < CHUNK / 16; ++k) {
    int v = vl + 16 * k;
    float4 p = vp[v];
#pragma unroll
    for (int j = 0; j < 4; ++j) {
      float t = fmaf(p.x, Ax[j], fmaf(p.y, Ay[j], fmaf(p.z, Az[j], p.w)));
      if (t <= TH[j]) {
        int l = lg + 16 * j;
        unsigned pidx = atomicAdd(&cnt[b * LA + l], 1u);
        if (pidx < (unsigned)cap) cand[(size_t)(b * LA + l) * cap + pidx] = base + v;
      }
    }
  }
}

// ---------------- K3: exact top-10 over candidates + set dedup bits -------------
// grid 2048 (=B_*LA), block 64 (one wave).
__global__ void k3_select(const float* __restrict__ pos,
                          const float* __restrict__ lig,
                          const unsigned int* __restrict__ cnt,
                          const int* __restrict__ cand, int cap,
                          unsigned int* __restrict__ maskG) {
  const int bl = blockIdx.x;
  const int b = bl / LA;
  const int lane = threadIdx.x;
  const float lx = lig[bl * 3 + 0], ly = lig[bl * 3 + 1], lz = lig[bl * 3 + 2];
  int n = (int)min(cnt[bl], (unsigned)cap);
  unsigned long long s[TOPK];
#pragma unroll
  for (int i = 0; i < TOPK; ++i) s[i] = 0xFFFFFFFFFFFFFFFFull;
  const float* pb = pos + (size_t)b * NV * 3;
  for (int i = lane; i < n; i += 64) {
    int v = cand[(size_t)bl * cap + i];
    float dx = pb[v * 3 + 0] - lx;
    float dy = pb[v * 3 + 1] - ly;
    float dz = pb[v * 3 + 2] - lz;
    float d2 = fmaf(dx, dx, fmaf(dy, dy, dz * dz));
    unsigned long long key =
        ((unsigned long long)__float_as_uint(d2) << 32) | (unsigned int)v;
    if (key < s[TOPK - 1]) {
      s[TOPK - 1] = key;
#pragma unroll
      for (int i2 = TOPK - 1; i2 >= 1; --i2)
        if (s[i2] < s[i2 - 1]) {
          unsigned long long t = s[i2]; s[i2] = s[i2 - 1]; s[i2 - 1] = t;
        }
    }
  }
  int prev = 0, myidx = 0;
  for (int r = 0; r < TOPK; ++r) {
    unsigned long long v = s[0];
#pragma unroll
    for (int o = 1; o < 64; o <<= 1) {
      unsigned long long other = __shfl_xor(v, o, 64);
      v = (other < v) ? other : v;
    }
    if (s[0] == v) {
#pragma unroll
      for (int i = 0; i < TOPK - 1; ++i) s[i] = s[i + 1];
      s[TOPK - 1] = 0xFFFFFFFFFFFFFFFFull;
    }
    int idx = (int)(unsigned int)(v & 0xFFFFFFFFu);
    if ((v >> 32) == 0xFFFFFFFFull) idx = prev;
    prev = idx;
    if (lane == r) myidx = idx;
  }
  if (lane < TOPK)
    atomicOr(&maskG[b * NMW + (myidx >> 5)], 1u << (myidx & 31));
}

// ---------------- K4a: mask compaction + parallel segment gather (f64) ----------
// grid (NSEG, B_), block 256. Each block rebuilds the sorted unique list in LDS
// (cheap: 1024 words), then gathers its 1/NSEG row range.
__global__ void k4a_gather(const float* __restrict__ x,
                           const unsigned int* __restrict__ maskG,
                           int* __restrict__ cntU,
                           double* __restrict__ partial) {
  __shared__ int list[MAXU];     // 2.56 KB
  __shared__ int wtot[4], wbase[4];
  __shared__ int cntS;
  __shared__ double red[2][DIM]; // 2 KB
  const int seg = blockIdx.x, b = blockIdx.y, tid = threadIdx.x;
  const int w = tid >> 6, lane = tid & 63;
  unsigned int wd[4];
  int c = 0;
#pragma unroll
  for (int k = 0; k < 4; ++k) {
    wd[k] = maskG[b * NMW + tid * 4 + k];
    c += __popc(wd[k]);
  }
  int incl = c;
#pragma unroll
  for (int o = 1; o < 64; o <<= 1) {
    int up = __shfl_up(incl, o, 64);
    if (lane >= o) incl += up;
  }
  if (lane == 63) wtot[w] = incl;
  __syncthreads();
  if (tid == 0) {
    int s = 0;
#pragma unroll
    for (int i = 0; i < 4; ++i) { wbase[i] = s; s += wtot[i]; }
    cntS = s;
  }
  __syncthreads();
  int p = wbase[w] + incl - c;
#pragma unroll
  for (int k = 0; k < 4; ++k) {
    unsigned int bits = wd[k];
    while (bits) {
      int bit = __ffs(bits) - 1;
      list[p++] = (tid * 4 + k) * 32 + bit;
      bits &= bits - 1;
    }
  }
  __syncthreads();
  const int n = cntS;
  if (seg == 0 && tid == 0) cntU[b] = n;
  const int r0 = (seg * n) / NSEG, r1 = ((seg + 1) * n) / NSEG;
  const int slot = tid >> 7, col = tid & 127;  // 2 row-slots x 128 cols
  const float* xb = x + (size_t)b * NV * DIM;
  double a0 = 0, a1 = 0, a2 = 0, a3 = 0;
  int i = r0 + slot;
  for (; i + 6 < r1; i += 8) {
    float v0 = xb[(size_t)list[i + 0] * DIM + col];
    float v1 = xb[(size_t)list[i + 2] * DIM + col];
    float v2 = xb[(size_t)list[i + 4] * DIM + col];
    float v3 = xb[(size_t)list[i + 6] * DIM + col];
    a0 += (double)v0; a1 += (double)v1; a2 += (double)v2; a3 += (double)v3;
  }
  for (; i < r1; i += 2) a0 += (double)xb[(size_t)list[i] * DIM + col];
  red[slot][col] = ((a0 + a1) + (a2 + a3));
  __syncthreads();
  if (tid < DIM)
    partial[((size_t)b * NSEG + seg) * DIM + tid] = red[0][tid] + red[1][tid];
}

// ---------------- K4b: reduce partials + top_net MLP ----------------------------
// grid B_, block 128 (= DIM).
__global__ void k4b_mlp(const double* __restrict__ partial,
                        const int* __restrict__ cntU,
                        const float* __restrict__ W1, const float* __restrict__ b1,
                        const float* __restrict__ gamma, const float* __restrict__ beta,
                        const float* __restrict__ rm, const float* __restrict__ rv,
                        const float* __restrict__ W2, const float* __restrict__ b2,
                        float* __restrict__ out) {
  __shared__ float embS[DIM];
  __shared__ float hS[DIM];
  const int b = blockIdx.x, d = threadIdx.x;
  double s = 0;
#pragma unroll
  for (int seg = 0; seg < NSEG; ++seg)
    s += partial[((size_t)b * NSEG + seg) * DIM + d];
  embS[d] = (float)(s / (double)cntU[b]);
  __syncthreads();
  float h = b1[d];
  for (int dd = 0; dd < DIM; ++dd) h = fmaf(embS[dd], W1[dd * DIM + d], h);
  h = (h - rm[d]) / sqrtf(rv[d] + 1e-5f) * gamma[d] + beta[d];
  h = h / (1.f + expf(-h));
  hS[d] = h;
  __syncthreads();
  if (d < OUTD) {
    float o = b2[d];
    for (int dd = 0; dd < DIM; ++dd) o = fmaf(hS[dd], W2[dd * OUTD + d], o);
    out[b * OUTD + d] = o;
  }
}

extern "C" void kernel_launch(void* const* d_in, const int* in_sizes, int n_in,
                              void* d_out, int out_size, void* d_ws, size_t ws_size,
                              hipStream_t stream) {
  const float* pos  = (const float*)d_in[0];
  const float* x    = (const float*)d_in[1];
  const float* lig  = (const float*)d_in[2];
  const float* W1   = (const float*)d_in[3];
  const float* b1   = (const float*)d_in[4];
  const float* gam  = (const float*)d_in[5];
  const float* bet  = (const float*)d_in[6];
  const float* rm   = (const float*)d_in[7];
  const float* rv   = (const float*)d_in[8];
  const float* W2   = (const float*)d_in[9];
  const float* b2   = (const float*)d_in[10];
  float* out = (float*)d_out;

  // workspace carve-up
  char* ws = (char*)d_ws;
  const int NBL = B_ * LA;  // 2048
  float* T            = (float*)(ws);                     // 8 KB
  unsigned int* cnt   = (unsigned int*)(ws + 8192);       // 8 KB
  unsigned int* maskG = (unsigned int*)(ws + 16384);      // 128 KB
  int* cntU           = (int*)(ws + 147456);              // 128 B
  double* partial     = (double*)(ws + 147584);           // 256 KB
  int* cand           = (int*)(ws + 409728);
  size_t fixed = 409728;
  size_t avail = ws_size > fixed ? ws_size - fixed : 0;
  int cap = (int)(avail / ((size_t)NBL * 4));
  if (cap > 1024) cap = 1024;
  if (cap < 16) cap = 16;

  k1_threshold<<<dim3(LA, B_), 64, 0, stream>>>(pos, lig, T, cnt, maskG);
  k2_filter<<<dim3(NCH, B_), 256, 0, stream>>>(pos, lig, T, cnt, cand, cap);
  k3_select<<<NBL, 64, 0, stream>>>(pos, lig, cnt, cand, cap, maskG);
  k4a_gather<<<dim3(NSEG, B_), 256, 0, stream>>>(x, maskG, cntU, partial);
  k4b_mlp<<<B_, 128, 0, stream>>>(partial, cntU, W1, b1, gam, bet, rm, rv, W2, b2, out);
}